// Round 19
// baseline (233.604 us; speedup 1.0000x reference)
//
#include <hip/hip_runtime.h>

typedef __attribute__((ext_vector_type(8))) short bf16x8;
typedef __attribute__((ext_vector_type(4))) float f32x4;
typedef __attribute__((ext_vector_type(4))) unsigned u32x4;

#define DEV static __device__ __forceinline__

constexpr int B_ = 2, H_ = 16, L_ = 2048, D_ = 64;
constexpr float SCALE2 = 0.125f * 1.44269504f;  // 1/sqrt(64) * log2(e)

DEV short f2bf(float f) {
  unsigned u = __builtin_bit_cast(unsigned, f);
  u += 0x7fffu + ((u >> 16) & 1u);  // RNE
  return (short)(u >> 16);
}
DEV unsigned pk2(float lo, float hi) {
  return (unsigned)(unsigned short)f2bf(lo) | ((unsigned)(unsigned short)f2bf(hi) << 16);
}
DEV float bflo(unsigned u) { return __builtin_bit_cast(float, u << 16); }
DEV float bfhi(unsigned u) { return __builtin_bit_cast(float, u & 0xffff0000u); }

DEV bf16x8 frag_from(const float* src) {  // 8 consecutive f32 -> bf16x8
  float4 f0 = *(const float4*)src;
  float4 f1 = *(const float4*)(src + 4);
  bf16x8 r;
  r[0] = f2bf(f0.x); r[1] = f2bf(f0.y); r[2] = f2bf(f0.z); r[3] = f2bf(f0.w);
  r[4] = f2bf(f1.x); r[5] = f2bf(f1.y); r[6] = f2bf(f1.z); r[7] = f2bf(f1.w);
  return r;
}

// ---------------- Pre-pass 1: K (f32) -> fragment-linear bf16 ----------------
__global__ __launch_bounds__(256) void convert_k_kernel(
    const float* __restrict__ Kg, short* __restrict__ Kp) {
  const int tid = threadIdx.x;
  const int lane = tid & 63, half = (tid >> 6) & 1, sub = tid >> 7;
  const int blk = blockIdx.x;                   // 2048 blocks
  const int bh = blk >> 6;                      // 32
  const int ktile = (((blk & 63) << 1) | sub);  // 0..127
  const int g = lane >> 4, ln = lane & 15;
  const float* src = Kg + ((size_t)bh * L_ + ktile * 16 + ln) * D_ + half * 32 + g * 8;
  bf16x8 f = frag_from(src);
  *(bf16x8*)(Kp + ((size_t)bh * 16384 + ktile * 128 + half * 64 + lane) * 8) = f;
}

// ---------------- Pre-pass 2: V (f32) -> fragment-linear bf16 Vp ----------------
// Vp unit (16B): idx = (bh*8 + c)*2048 + (n*8 + w)*64 + lane, lane=(g,ln):
// {V[k0+e][d] e=0..3, V[k0+16+e][d] e=0..3} bf16, k0 = c*256 + w*32 + g*4,
// d = n*16+ln.  (Exactly one PV B-fragment for the paired-tile mapping.)
__global__ __launch_bounds__(256) void convert_vp_kernel(
    const float* __restrict__ Vg, short* __restrict__ Vp) {
  __shared__ short vt[64 * 256];  // [d][k 0..255] bf16, XOR-swizzled rows of 512B
  const int tid = threadIdx.x;
  const int bh = blockIdx.x >> 3, c = blockIdx.x & 7;
  const float* vb = Vg + (size_t)bh * L_ * D_ + (size_t)c * 256 * D_;
  const int ka = (tid & 127) * 2, dh = (tid >> 7) * 32;
  const float* r0 = vb + (size_t)ka * D_ + dh;
  const float* r1 = r0 + D_;
#pragma unroll
  for (int i = 0; i < 8; ++i) {
    float4 a = *(const float4*)(r0 + i * 4);
    float4 b = *(const float4*)(r1 + i * 4);
    unsigned p0 = pk2(a.x, b.x), p1 = pk2(a.y, b.y), p2 = pk2(a.z, b.z), p3 = pk2(a.w, b.w);
    const int dd = dh + i * 4;
    *(unsigned*)((char*)vt + (dd + 0) * 512 + ((ka * 2) ^ (((dd + 0) & 7) << 4))) = p0;
    *(unsigned*)((char*)vt + (dd + 1) * 512 + ((ka * 2) ^ (((dd + 1) & 7) << 4))) = p1;
    *(unsigned*)((char*)vt + (dd + 2) * 512 + ((ka * 2) ^ (((dd + 2) & 7) << 4))) = p2;
    *(unsigned*)((char*)vt + (dd + 3) * 512 + ((ka * 2) ^ (((dd + 3) & 7) << 4))) = p3;
  }
  __syncthreads();
  u32x4* out = (u32x4*)Vp + (size_t)(bh * 8 + c) * 2048;
#pragma unroll
  for (int i = 0; i < 8; ++i) {
    const int u = tid + 256 * i;
    const int lane = u & 63, w = (u >> 6) & 7, n = u >> 9;
    const int g = lane >> 4, ln = lane & 15;
    const int d = n * 16 + ln;
    const int kb = (w * 32 + g * 4) * 2;  // byte offset of k0 within row
    const char* rowp = (const char*)vt + d * 512;
    const int swz = (d & 7) << 4;
    uint2 lo = *(const uint2*)(rowp + (kb ^ swz));
    uint2 hi = *(const uint2*)(rowp + ((kb + 32) ^ swz));
    out[u] = u32x4{lo.x, lo.y, hi.x, hi.y};
  }
}

// ---------------- Fused kernel ----------------
// 512 threads (8 waves), q-tile 16 rows. Swapped QK^T: mfma(K,Q); wave w owns
// paired tiles 2w+16i+{0,1} -> full-line P stores. PV: chunk c staged into a
// SINGLE 32KB LDS buffer (write-after-read barrier) via T14 async-split.
// LDS 33KB -> 4 blocks/CU (32 waves, ~2x the latency-hiding pool of r18).
// 4-head-group decode (r18): FETCH at compulsory minimum.
template <bool USEPRE>
__global__ __launch_bounds__(512, 4) void attn_fused(
    const float* __restrict__ Qg, const float* __restrict__ Kg,
    const short* __restrict__ Kp, const float* __restrict__ Vg,
    const short* __restrict__ Vpg, const float* __restrict__ Mg,
    float* __restrict__ Pg, float* __restrict__ Og) {
  const int tid = threadIdx.x;
  const int w = tid >> 6, lane = tid & 63;
  const int g = lane >> 4, ln = lane & 15;

  // 4096 blocks = 8 XCD chunks x 512; chunk = 1 head-group (4 bh) x 128 qt.
  const int bid = blockIdx.x;
  const int wg = (bid & 7) * 512 + (bid >> 3);
  const int grp = wg >> 9;          // 0..7: head group (4 heads)
  const int idx = wg & 511;
  const int qt = idx >> 2;          // 0..127
  const int bh = grp * 4 + (idx & 3);
  const int q0 = qt << 4;
  const int b = bh >> 4;  // H_=16

  __shared__ u32x4 vstage[2048];  // 32 KB single-buffer fragment-linear V chunk
  __shared__ float red[8][16];

  const float* qp = Qg + (size_t)bh * L_ * D_;
  const float* mrow = Mg + (size_t)b * L_ * L_ + (size_t)(q0 + ln) * L_;
  float* prow = Pg + (size_t)bh * L_ * L_ + (size_t)(q0 + ln) * L_;

  bf16x8 qf0 = frag_from(qp + (size_t)(q0 + ln) * D_ + g * 8);
  bf16x8 qf1 = frag_from(qp + (size_t)(q0 + ln) * D_ + 32 + g * 8);

  unsigned pkv[32];
  float mx = -1e30f;
  const bf16x8* kb_ = (const bf16x8*)Kp + (size_t)bh * 16384 + lane;

#define TILE_OF(j) (2 * w + (((j) >> 1) << 4) + ((j) & 1))

  // ---- QK^T with explicit 1-deep prefetch of K-frags and mask ----
  bf16x8 k0c, k1c, k0n, k1n;
  float4 mkc, mkn;
  {
    const int t0 = TILE_OF(0);
    if (USEPRE) {
      k0c = kb_[t0 * 128];
      k1c = kb_[t0 * 128 + 64];
    } else {
      const float* kr = Kg + (size_t)bh * L_ * D_ + (size_t)(t0 * 16 + ln) * D_;
      k0c = frag_from(kr + g * 8);
      k1c = frag_from(kr + 32 + g * 8);
    }
    mkc = *(const float4*)(mrow + t0 * 16 + g * 4);
  }
#pragma unroll
  for (int j = 0; j < 16; ++j) {
    if (j < 15) {
      const int tn = TILE_OF(j + 1);
      if (USEPRE) {
        k0n = kb_[tn * 128];
        k1n = kb_[tn * 128 + 64];
      } else {
        const float* kr = Kg + (size_t)bh * L_ * D_ + (size_t)(tn * 16 + ln) * D_;
        k0n = frag_from(kr + g * 8);
        k1n = frag_from(kr + 32 + g * 8);
      }
      mkn = *(const float4*)(mrow + tn * 16 + g * 4);
    }
    f32x4 acc{0.f, 0.f, 0.f, 0.f};
    acc = __builtin_amdgcn_mfma_f32_16x16x32_bf16(k0c, qf0, acc, 0, 0, 0);
    acc = __builtin_amdgcn_mfma_f32_16x16x32_bf16(k1c, qf1, acc, 0, 0, 0);
    float l0 = acc[0] * SCALE2 * mkc.x;   // log2-domain logits
    float l1 = acc[1] * SCALE2 * mkc.y;
    float l2 = acc[2] * SCALE2 * mkc.z;
    float l3 = acc[3] * SCALE2 * mkc.w;
    mx = fmaxf(mx, fmaxf(fmaxf(l0, l1), fmaxf(l2, l3)));
    pkv[2 * j] = pk2(l0, l1);
    pkv[2 * j + 1] = pk2(l2, l3);
    k0c = k0n; k1c = k1n; mkc = mkn;
  }

  // ---- issue chunk-0 stage loads; land during softmax (T14 split) ----
  const u32x4* vp4 = (const u32x4*)Vpg + (size_t)bh * 8 * 2048;
  u32x4 sv0, sv1, sv2, sv3;
  if (USEPRE) {
    sv0 = vp4[0 * 512 + tid];
    sv1 = vp4[1 * 512 + tid];
    sv2 = vp4[2 * 512 + tid];
    sv3 = vp4[3 * 512 + tid];
  }

  // ---- softmax (q-row ln per lane), exp2 domain ----
  mx = fmaxf(mx, __shfl_xor(mx, 16));
  mx = fmaxf(mx, __shfl_xor(mx, 32));
  if (lane < 16) red[w][ln] = mx;
  __syncthreads();
  {
    float t = red[0][ln];
#pragma unroll
    for (int ww = 1; ww < 8; ++ww) t = fmaxf(t, red[ww][ln]);
    mx = t;
  }
  float sm = 0.f;
#pragma unroll
  for (int j = 0; j < 16; ++j) {
    float e0 = exp2f(bflo(pkv[2 * j]) - mx);
    float e1 = exp2f(bfhi(pkv[2 * j]) - mx);
    float e2 = exp2f(bflo(pkv[2 * j + 1]) - mx);
    float e3 = exp2f(bfhi(pkv[2 * j + 1]) - mx);
    sm += (e0 + e1) + (e2 + e3);
    pkv[2 * j] = pk2(e0, e1);
    pkv[2 * j + 1] = pk2(e2, e3);
  }
  sm += __shfl_xor(sm, 16);
  sm += __shfl_xor(sm, 32);
  __syncthreads();  // max-phase readers done with red
  if (lane < 16) red[w][ln] = sm;
  // write chunk-0 stage to LDS here; ordered before PV reads by the barrier
  if (USEPRE) {
    vstage[0 * 512 + tid] = sv0;
    vstage[1 * 512 + tid] = sv1;
    vstage[2 * 512 + tid] = sv2;
    vstage[3 * 512 + tid] = sv3;
  }
  __syncthreads();
  float inv;
  {
    float t = red[0][ln];
#pragma unroll
    for (int ww = 1; ww < 8; ++ww) t += red[ww][ln];
    inv = 1.0f / t;
  }

  // ---- PV + P-write, chunk c = tile pair (2w+16c, 2w+16c+1) ----
  // Single LDS buffer: MFMA chunk c -> barrier (reads done) -> write c+1 ->
  // barrier. c+1's loads were issued at the top of iteration c (T14).
  f32x4 acc_o[4];
#pragma unroll
  for (int n = 0; n < 4; ++n) acc_o[n] = f32x4{0.f, 0.f, 0.f, 0.f};

  const float* vsrc_f32 = Vg + (size_t)bh * L_ * D_;

#pragma unroll
  for (int c = 0; c < 8; ++c) {
    // T14: issue next chunk's global loads FIRST (hide under compute below)
    if (USEPRE && c < 7) {
      sv0 = vp4[(size_t)(c + 1) * 2048 + 0 * 512 + tid];
      sv1 = vp4[(size_t)(c + 1) * 2048 + 1 * 512 + tid];
      sv2 = vp4[(size_t)(c + 1) * 2048 + 2 * 512 + tid];
      sv3 = vp4[(size_t)(c + 1) * 2048 + 3 * 512 + tid];
    }
    // normalize this chunk's 8 P values; store full 128B line per lane-row
    unsigned u0 = pkv[4 * c], u1 = pkv[4 * c + 1], u2 = pkv[4 * c + 2], u3 = pkv[4 * c + 3];
    float n0 = bflo(u0) * inv, n1 = bfhi(u0) * inv;
    float n2 = bflo(u1) * inv, n3 = bfhi(u1) * inv;
    float n4 = bflo(u2) * inv, n5 = bfhi(u2) * inv;
    float n6 = bflo(u3) * inv, n7 = bfhi(u3) * inv;
    const int te = 2 * w + 16 * c;
    f32x4 s0{n0, n1, n2, n3};
    f32x4 s1{n4, n5, n6, n7};
    __builtin_nontemporal_store(s0, (f32x4*)(prow + te * 16 + g * 4));
    __builtin_nontemporal_store(s1, (f32x4*)(prow + (te + 1) * 16 + g * 4));
    u32x4 au{pk2(n0, n1), pk2(n2, n3), pk2(n4, n5), pk2(n6, n7)};
    bf16x8 pa = __builtin_bit_cast(bf16x8, au);
    // MFMA from LDS (fragment-linear: fully conflict-free b128 reads)
#pragma unroll
    for (int n = 0; n < 4; ++n) {
      bf16x8 bf;
      if (USEPRE) {
        bf = __builtin_bit_cast(bf16x8, vstage[(n * 8 + w) * 64 + lane]);
      } else {
        const int k0i = c * 256 + w * 32 + g * 4;
        const int d = n * 16 + ln;
        const float* vbp = vsrc_f32 + d;
#pragma unroll
        for (int e = 0; e < 4; ++e) bf[e] = f2bf(vbp[(size_t)(k0i + e) * D_]);
#pragma unroll
        for (int e = 0; e < 4; ++e) bf[4 + e] = f2bf(vbp[(size_t)(k0i + 16 + e) * D_]);
      }
      acc_o[n] = __builtin_amdgcn_mfma_f32_16x16x32_bf16(pa, bf, acc_o[n], 0, 0, 0);
    }
    __syncthreads();  // all reads of chunk c done
    if (USEPRE && c < 7) {
      vstage[0 * 512 + tid] = sv0;
      vstage[1 * 512 + tid] = sv1;
      vstage[2 * 512 + tid] = sv2;
      vstage[3 * 512 + tid] = sv3;
      __syncthreads();  // chunk c+1 visible
    }
  }

  // ---- 8-way O-partial reduce (alias vstage) + write O ----
  float* red_o = (float*)&vstage[0];  // 32 KB
#pragma unroll
  for (int n = 0; n < 4; ++n)
#pragma unroll
    for (int r = 0; r < 4; ++r)
      red_o[(w * 16 + g * 4 + r) * 64 + n * 16 + ln] = acc_o[n][r];
  __syncthreads();
  {
    float* ob = Og + (size_t)bh * L_ * D_ + (size_t)q0 * D_;
    const int row = tid >> 5, dp = (tid & 31) * 2;
    float s0 = 0.f, s1 = 0.f;
#pragma unroll
    for (int ww = 0; ww < 8; ++ww) {
      s0 += red_o[(ww * 16 + row) * 64 + dp];
      s1 += red_o[(ww * 16 + row) * 64 + dp + 1];
    }
    __builtin_nontemporal_store(s0, ob + row * D_ + dp);
    __builtin_nontemporal_store(s1, ob + row * D_ + dp + 1);
  }
}

extern "C" void kernel_launch(void* const* d_in, const int* in_sizes, int n_in,
                              void* d_out, int out_size, void* d_ws, size_t ws_size,
                              hipStream_t stream) {
  const float* q = (const float*)d_in[0];
  const float* k = (const float*)d_in[1];
  const float* v = (const float*)d_in[2];
  const float* mask = (const float*)d_in[3];
  float* out = (float*)d_out;                      // [B,H,L,D]
  float* score = out + (size_t)B_ * H_ * L_ * D_;  // [B,H,L,L]

  const size_t elems = (size_t)B_ * H_ * L_ * D_;  // 4.19M
  const size_t need = elems * 2 * sizeof(short);   // Kp + Vp = 16 MB
  const int nblk = B_ * H_ * (L_ / 16);            // 4096

  if (ws_size >= need) {
    short* kp = (short*)d_ws;
    short* vp = kp + elems;
    convert_k_kernel<<<2048, 256, 0, stream>>>(k, kp);
    convert_vp_kernel<<<B_ * H_ * 8, 256, 0, stream>>>(v, vp);
    attn_fused<true><<<nblk, 512, 0, stream>>>(q, k, kp, v, vp, mask, score, out);
  } else {
    attn_fused<false><<<nblk, 512, 0, stream>>>(q, k, nullptr, v, nullptr, mask, score, out);
  }
}

// Round 20
// 232.082 us; speedup vs baseline: 1.0066x; 1.0066x over previous
//
#include <hip/hip_runtime.h>

typedef __attribute__((ext_vector_type(8))) short bf16x8;
typedef __attribute__((ext_vector_type(4))) float f32x4;
typedef __attribute__((ext_vector_type(4))) unsigned u32x4;

#define DEV static __device__ __forceinline__

constexpr int B_ = 2, H_ = 16, L_ = 2048, D_ = 64;
constexpr float SCALE2 = 0.125f * 1.44269504f;  // 1/sqrt(64) * log2(e)

DEV short f2bf(float f) {
  unsigned u = __builtin_bit_cast(unsigned, f);
  u += 0x7fffu + ((u >> 16) & 1u);  // RNE
  return (short)(u >> 16);
}
DEV unsigned pk2(float lo, float hi) {
  return (unsigned)(unsigned short)f2bf(lo) | ((unsigned)(unsigned short)f2bf(hi) << 16);
}
DEV float bflo(unsigned u) { return __builtin_bit_cast(float, u << 16); }
DEV float bfhi(unsigned u) { return __builtin_bit_cast(float, u & 0xffff0000u); }

DEV bf16x8 frag_from(const float* src) {  // 8 consecutive f32 -> bf16x8
  float4 f0 = *(const float4*)src;
  float4 f1 = *(const float4*)(src + 4);
  bf16x8 r;
  r[0] = f2bf(f0.x); r[1] = f2bf(f0.y); r[2] = f2bf(f0.z); r[3] = f2bf(f0.w);
  r[4] = f2bf(f1.x); r[5] = f2bf(f1.y); r[6] = f2bf(f1.z); r[7] = f2bf(f1.w);
  return r;
}

// ---------------- Pre-pass 1: K (f32) -> fragment-linear bf16 ----------------
__global__ __launch_bounds__(256) void convert_k_kernel(
    const float* __restrict__ Kg, short* __restrict__ Kp) {
  const int tid = threadIdx.x;
  const int lane = tid & 63, half = (tid >> 6) & 1, sub = tid >> 7;
  const int blk = blockIdx.x;                   // 2048 blocks
  const int bh = blk >> 6;                      // 32
  const int ktile = (((blk & 63) << 1) | sub);  // 0..127
  const int g = lane >> 4, ln = lane & 15;
  const float* src = Kg + ((size_t)bh * L_ + ktile * 16 + ln) * D_ + half * 32 + g * 8;
  bf16x8 f = frag_from(src);
  *(bf16x8*)(Kp + ((size_t)bh * 16384 + ktile * 128 + half * 64 + lane) * 8) = f;
}

// ---------------- Pre-pass 2: V (f32) -> fragment-linear bf16 Vp ----------------
// Vp unit (16B): idx = (bh*8 + c)*2048 + (n*8 + w)*64 + lane, lane=(g,ln):
// {V[k0+e][d] e=0..3, V[k0+16+e][d] e=0..3} bf16, k0 = c*256 + w*32 + g*4,
// d = n*16+ln.  (Exactly one PV B-fragment for the paired-tile mapping.)
__global__ __launch_bounds__(256) void convert_vp_kernel(
    const float* __restrict__ Vg, short* __restrict__ Vp) {
  __shared__ short vt[64 * 256];  // [d][k 0..255] bf16, XOR-swizzled rows of 512B
  const int tid = threadIdx.x;
  const int bh = blockIdx.x >> 3, c = blockIdx.x & 7;
  const float* vb = Vg + (size_t)bh * L_ * D_ + (size_t)c * 256 * D_;
  const int ka = (tid & 127) * 2, dh = (tid >> 7) * 32;
  const float* r0 = vb + (size_t)ka * D_ + dh;
  const float* r1 = r0 + D_;
#pragma unroll
  for (int i = 0; i < 8; ++i) {
    float4 a = *(const float4*)(r0 + i * 4);
    float4 b = *(const float4*)(r1 + i * 4);
    unsigned p0 = pk2(a.x, b.x), p1 = pk2(a.y, b.y), p2 = pk2(a.z, b.z), p3 = pk2(a.w, b.w);
    const int dd = dh + i * 4;
    *(unsigned*)((char*)vt + (dd + 0) * 512 + ((ka * 2) ^ (((dd + 0) & 7) << 4))) = p0;
    *(unsigned*)((char*)vt + (dd + 1) * 512 + ((ka * 2) ^ (((dd + 1) & 7) << 4))) = p1;
    *(unsigned*)((char*)vt + (dd + 2) * 512 + ((ka * 2) ^ (((dd + 2) & 7) << 4))) = p2;
    *(unsigned*)((char*)vt + (dd + 3) * 512 + ((ka * 2) ^ (((dd + 3) & 7) << 4))) = p3;
  }
  __syncthreads();
  u32x4* out = (u32x4*)Vp + (size_t)(bh * 8 + c) * 2048;
#pragma unroll
  for (int i = 0; i < 8; ++i) {
    const int u = tid + 256 * i;
    const int lane = u & 63, w = (u >> 6) & 7, n = u >> 9;
    const int g = lane >> 4, ln = lane & 15;
    const int d = n * 16 + ln;
    const int kb = (w * 32 + g * 4) * 2;  // byte offset of k0 within row
    const char* rowp = (const char*)vt + d * 512;
    const int swz = (d & 7) << 4;
    uint2 lo = *(const uint2*)(rowp + (kb ^ swz));
    uint2 hi = *(const uint2*)(rowp + ((kb + 32) ^ swz));
    out[u] = u32x4{lo.x, lo.y, hi.x, hi.y};
  }
}

// ---------------- Pre-pass 3: mask (f32) -> fragment-linear Mp ----------------
// Mp unit (float4): idx = ((b*128 + qt)*128 + tile)*64 + lane, lane=(g,ln):
// mask[b][qt*16+ln][tile*16+g*4 .. +4].  QK mask loads become coalesced.
__global__ __launch_bounds__(256) void convert_m_kernel(
    const float* __restrict__ Mg, float* __restrict__ Mp) {
  const int tid = threadIdx.x;
  const int b = blockIdx.x >> 7, qt = blockIdx.x & 127;  // 256 blocks
  const float* src = Mg + (size_t)b * L_ * L_ + (size_t)qt * 16 * L_;
  f32x4* out = (f32x4*)Mp + ((size_t)(b * 128 + qt) * 128) * 64;
#pragma unroll
  for (int i = 0; i < 32; ++i) {
    const int u = tid + 256 * i;  // tile*64 + lane
    const int tile = u >> 6, lane = u & 63;
    const int g = (lane >> 4) & 3, ln = lane & 15;
    out[u] = *(const f32x4*)(src + (size_t)ln * L_ + tile * 16 + g * 4);
  }
}

// ---------------- Fused kernel ----------------
// 512 threads (8 waves), q-tile 16 rows. Swapped QK^T: mfma(K,Q); wave w owns
// paired tiles 2w+16i+{0,1} -> full-line P stores. PV: chunk c staged into a
// single 32KB LDS buffer (write-after-read barrier) via T14 async-split.
// 4-head-group decode (r18): FETCH at compulsory minimum. USEMP: mask reads
// from fragment-linear Mp (fully coalesced) instead of 8KB-stride gather.
template <bool USEPRE, bool USEMP>
__global__ __launch_bounds__(512, 4) void attn_fused(
    const float* __restrict__ Qg, const float* __restrict__ Kg,
    const short* __restrict__ Kp, const float* __restrict__ Vg,
    const short* __restrict__ Vpg, const float* __restrict__ Mg,
    const float* __restrict__ Mpg, float* __restrict__ Pg,
    float* __restrict__ Og) {
  const int tid = threadIdx.x;
  const int w = tid >> 6, lane = tid & 63;
  const int g = lane >> 4, ln = lane & 15;

  // 4096 blocks = 8 XCD chunks x 512; chunk = 1 head-group (4 bh) x 128 qt.
  const int bid = blockIdx.x;
  const int wg = (bid & 7) * 512 + (bid >> 3);
  const int grp = wg >> 9;          // 0..7: head group (4 heads)
  const int idx = wg & 511;
  const int qt = idx >> 2;          // 0..127
  const int bh = grp * 4 + (idx & 3);
  const int q0 = qt << 4;
  const int b = bh >> 4;  // H_=16

  __shared__ u32x4 vstage[2048];  // 32 KB single-buffer fragment-linear V chunk
  __shared__ float red[8][16];

  const float* qp = Qg + (size_t)bh * L_ * D_;
  const float* mrow = Mg + (size_t)b * L_ * L_ + (size_t)(q0 + ln) * L_;
  const f32x4* mp4 = (const f32x4*)Mpg + ((size_t)(b * 128 + qt) * 128) * 64 + lane;
  float* prow = Pg + (size_t)bh * L_ * L_ + (size_t)(q0 + ln) * L_;

  bf16x8 qf0 = frag_from(qp + (size_t)(q0 + ln) * D_ + g * 8);
  bf16x8 qf1 = frag_from(qp + (size_t)(q0 + ln) * D_ + 32 + g * 8);

  unsigned pkv[32];
  float mx = -1e30f;
  const bf16x8* kb_ = (const bf16x8*)Kp + (size_t)bh * 16384 + lane;

#define TILE_OF(j) (2 * w + (((j) >> 1) << 4) + ((j) & 1))
#define MK_LOAD(dst, t_)                                                \
  {                                                                     \
    if (USEMP) dst = __builtin_bit_cast(float4, mp4[(t_) * 64]);        \
    else dst = *(const float4*)(mrow + (t_) * 16 + g * 4);              \
  }

  // ---- QK^T with explicit 1-deep prefetch of K-frags and mask ----
  bf16x8 k0c, k1c, k0n, k1n;
  float4 mkc, mkn;
  {
    const int t0 = TILE_OF(0);
    if (USEPRE) {
      k0c = kb_[t0 * 128];
      k1c = kb_[t0 * 128 + 64];
    } else {
      const float* kr = Kg + (size_t)bh * L_ * D_ + (size_t)(t0 * 16 + ln) * D_;
      k0c = frag_from(kr + g * 8);
      k1c = frag_from(kr + 32 + g * 8);
    }
    MK_LOAD(mkc, t0)
  }
#pragma unroll
  for (int j = 0; j < 16; ++j) {
    if (j < 15) {
      const int tn = TILE_OF(j + 1);
      if (USEPRE) {
        k0n = kb_[tn * 128];
        k1n = kb_[tn * 128 + 64];
      } else {
        const float* kr = Kg + (size_t)bh * L_ * D_ + (size_t)(tn * 16 + ln) * D_;
        k0n = frag_from(kr + g * 8);
        k1n = frag_from(kr + 32 + g * 8);
      }
      MK_LOAD(mkn, tn)
    }
    f32x4 acc{0.f, 0.f, 0.f, 0.f};
    acc = __builtin_amdgcn_mfma_f32_16x16x32_bf16(k0c, qf0, acc, 0, 0, 0);
    acc = __builtin_amdgcn_mfma_f32_16x16x32_bf16(k1c, qf1, acc, 0, 0, 0);
    float l0 = acc[0] * SCALE2 * mkc.x;   // log2-domain logits
    float l1 = acc[1] * SCALE2 * mkc.y;
    float l2 = acc[2] * SCALE2 * mkc.z;
    float l3 = acc[3] * SCALE2 * mkc.w;
    mx = fmaxf(mx, fmaxf(fmaxf(l0, l1), fmaxf(l2, l3)));
    pkv[2 * j] = pk2(l0, l1);
    pkv[2 * j + 1] = pk2(l2, l3);
    k0c = k0n; k1c = k1n; mkc = mkn;
  }

  // ---- issue chunk-0 stage loads; land during softmax (T14 split) ----
  const u32x4* vp4 = (const u32x4*)Vpg + (size_t)bh * 8 * 2048;
  u32x4 sv0, sv1, sv2, sv3;
  if (USEPRE) {
    sv0 = vp4[0 * 512 + tid];
    sv1 = vp4[1 * 512 + tid];
    sv2 = vp4[2 * 512 + tid];
    sv3 = vp4[3 * 512 + tid];
  }

  // ---- softmax (q-row ln per lane), exp2 domain ----
  mx = fmaxf(mx, __shfl_xor(mx, 16));
  mx = fmaxf(mx, __shfl_xor(mx, 32));
  if (lane < 16) red[w][ln] = mx;
  __syncthreads();
  {
    float t = red[0][ln];
#pragma unroll
    for (int ww = 1; ww < 8; ++ww) t = fmaxf(t, red[ww][ln]);
    mx = t;
  }
  float sm = 0.f;
#pragma unroll
  for (int j = 0; j < 16; ++j) {
    float e0 = exp2f(bflo(pkv[2 * j]) - mx);
    float e1 = exp2f(bfhi(pkv[2 * j]) - mx);
    float e2 = exp2f(bflo(pkv[2 * j + 1]) - mx);
    float e3 = exp2f(bfhi(pkv[2 * j + 1]) - mx);
    sm += (e0 + e1) + (e2 + e3);
    pkv[2 * j] = pk2(e0, e1);
    pkv[2 * j + 1] = pk2(e2, e3);
  }
  sm += __shfl_xor(sm, 16);
  sm += __shfl_xor(sm, 32);
  __syncthreads();  // max-phase readers done with red
  if (lane < 16) red[w][ln] = sm;
  // write chunk-0 stage to LDS here; ordered before PV reads by the barrier
  if (USEPRE) {
    vstage[0 * 512 + tid] = sv0;
    vstage[1 * 512 + tid] = sv1;
    vstage[2 * 512 + tid] = sv2;
    vstage[3 * 512 + tid] = sv3;
  }
  __syncthreads();
  float inv;
  {
    float t = red[0][ln];
#pragma unroll
    for (int ww = 1; ww < 8; ++ww) t += red[ww][ln];
    inv = 1.0f / t;
  }

  // ---- PV + P-write, chunk c = tile pair (2w+16c, 2w+16c+1) ----
  f32x4 acc_o[4];
#pragma unroll
  for (int n = 0; n < 4; ++n) acc_o[n] = f32x4{0.f, 0.f, 0.f, 0.f};

  const float* vsrc_f32 = Vg + (size_t)bh * L_ * D_;

#pragma unroll
  for (int c = 0; c < 8; ++c) {
    // T14: issue next chunk's global loads FIRST (hide under compute below)
    if (USEPRE && c < 7) {
      sv0 = vp4[(size_t)(c + 1) * 2048 + 0 * 512 + tid];
      sv1 = vp4[(size_t)(c + 1) * 2048 + 1 * 512 + tid];
      sv2 = vp4[(size_t)(c + 1) * 2048 + 2 * 512 + tid];
      sv3 = vp4[(size_t)(c + 1) * 2048 + 3 * 512 + tid];
    }
    // normalize this chunk's 8 P values; store full 128B line per lane-row
    unsigned u0 = pkv[4 * c], u1 = pkv[4 * c + 1], u2 = pkv[4 * c + 2], u3 = pkv[4 * c + 3];
    float n0 = bflo(u0) * inv, n1 = bfhi(u0) * inv;
    float n2 = bflo(u1) * inv, n3 = bfhi(u1) * inv;
    float n4 = bflo(u2) * inv, n5 = bfhi(u2) * inv;
    float n6 = bflo(u3) * inv, n7 = bfhi(u3) * inv;
    const int te = 2 * w + 16 * c;
    f32x4 s0{n0, n1, n2, n3};
    f32x4 s1{n4, n5, n6, n7};
    __builtin_nontemporal_store(s0, (f32x4*)(prow + te * 16 + g * 4));
    __builtin_nontemporal_store(s1, (f32x4*)(prow + (te + 1) * 16 + g * 4));
    u32x4 au{pk2(n0, n1), pk2(n2, n3), pk2(n4, n5), pk2(n6, n7)};
    bf16x8 pa = __builtin_bit_cast(bf16x8, au);
    // MFMA from LDS (fragment-linear: fully conflict-free b128 reads)
#pragma unroll
    for (int n = 0; n < 4; ++n) {
      bf16x8 bf;
      if (USEPRE) {
        bf = __builtin_bit_cast(bf16x8, vstage[(n * 8 + w) * 64 + lane]);
      } else {
        const int k0i = c * 256 + w * 32 + g * 4;
        const int d = n * 16 + ln;
        const float* vbp = vsrc_f32 + d;
#pragma unroll
        for (int e = 0; e < 4; ++e) bf[e] = f2bf(vbp[(size_t)(k0i + e) * D_]);
#pragma unroll
        for (int e = 0; e < 4; ++e) bf[4 + e] = f2bf(vbp[(size_t)(k0i + 16 + e) * D_]);
      }
      acc_o[n] = __builtin_amdgcn_mfma_f32_16x16x32_bf16(pa, bf, acc_o[n], 0, 0, 0);
    }
    __syncthreads();  // all reads of chunk c done
    if (USEPRE && c < 7) {
      vstage[0 * 512 + tid] = sv0;
      vstage[1 * 512 + tid] = sv1;
      vstage[2 * 512 + tid] = sv2;
      vstage[3 * 512 + tid] = sv3;
      __syncthreads();  // chunk c+1 visible
    }
  }

  // ---- 8-way O-partial reduce (alias vstage) + write O ----
  float* red_o = (float*)&vstage[0];  // 32 KB
#pragma unroll
  for (int n = 0; n < 4; ++n)
#pragma unroll
    for (int r = 0; r < 4; ++r)
      red_o[(w * 16 + g * 4 + r) * 64 + n * 16 + ln] = acc_o[n][r];
  __syncthreads();
  {
    float* ob = Og + (size_t)bh * L_ * D_ + (size_t)q0 * D_;
    const int row = tid >> 5, dp = (tid & 31) * 2;
    float s0 = 0.f, s1 = 0.f;
#pragma unroll
    for (int ww = 0; ww < 8; ++ww) {
      s0 += red_o[(ww * 16 + row) * 64 + dp];
      s1 += red_o[(ww * 16 + row) * 64 + dp + 1];
    }
    __builtin_nontemporal_store(s0, ob + row * D_ + dp);
    __builtin_nontemporal_store(s1, ob + row * D_ + dp + 1);
  }
}

extern "C" void kernel_launch(void* const* d_in, const int* in_sizes, int n_in,
                              void* d_out, int out_size, void* d_ws, size_t ws_size,
                              hipStream_t stream) {
  const float* q = (const float*)d_in[0];
  const float* k = (const float*)d_in[1];
  const float* v = (const float*)d_in[2];
  const float* mask = (const float*)d_in[3];
  float* out = (float*)d_out;                      // [B,H,L,D]
  float* score = out + (size_t)B_ * H_ * L_ * D_;  // [B,H,L,L]

  const size_t elems = (size_t)B_ * H_ * L_ * D_;   // 4.19M
  const size_t kv_bytes = elems * 2 * sizeof(short);    // Kp + Vp = 16 MB
  const size_t m_bytes = (size_t)B_ * L_ * L_ * 4;      // Mp = 33.5 MB
  const int nblk = B_ * H_ * (L_ / 16);             // 4096

  if (ws_size >= kv_bytes + m_bytes) {
    short* kp = (short*)d_ws;
    short* vp = kp + elems;
    float* mp = (float*)(vp + elems);
    convert_k_kernel<<<2048, 256, 0, stream>>>(k, kp);
    convert_vp_kernel<<<B_ * H_ * 8, 256, 0, stream>>>(v, vp);
    convert_m_kernel<<<B_ * 128, 256, 0, stream>>>(mask, mp);
    attn_fused<true, true><<<nblk, 512, 0, stream>>>(q, k, kp, v, vp, mask, mp, score, out);
  } else if (ws_size >= kv_bytes) {
    short* kp = (short*)d_ws;
    short* vp = kp + elems;
    convert_k_kernel<<<2048, 256, 0, stream>>>(k, kp);
    convert_vp_kernel<<<B_ * H_ * 8, 256, 0, stream>>>(v, vp);
    attn_fused<true, false><<<nblk, 512, 0, stream>>>(q, k, kp, v, vp, mask, nullptr, score, out);
  } else {
    attn_fused<false, false><<<nblk, 512, 0, stream>>>(q, k, nullptr, v, nullptr, mask, nullptr, score, out);
  }
}

// Round 22
// 231.097 us; speedup vs baseline: 1.0108x; 1.0043x over previous
//
#include <hip/hip_runtime.h>

typedef __attribute__((ext_vector_type(8))) short bf16x8;
typedef __attribute__((ext_vector_type(4))) float f32x4;
typedef __attribute__((ext_vector_type(4))) unsigned u32x4;

#define DEV static __device__ __forceinline__

constexpr int B_ = 2, H_ = 16, L_ = 2048, D_ = 64;
constexpr float SCALE2 = 0.125f * 1.44269504f;  // 1/sqrt(64) * log2(e)

DEV short f2bf(float f) {
  unsigned u = __builtin_bit_cast(unsigned, f);
  u += 0x7fffu + ((u >> 16) & 1u);  // RNE
  return (short)(u >> 16);
}
DEV unsigned pk2(float lo, float hi) {
  return (unsigned)(unsigned short)f2bf(lo) | ((unsigned)(unsigned short)f2bf(hi) << 16);
}
DEV float bflo(unsigned u) { return __builtin_bit_cast(float, u << 16); }
DEV float bfhi(unsigned u) { return __builtin_bit_cast(float, u & 0xffff0000u); }

DEV bf16x8 frag_from(const float* src) {  // 8 consecutive f32 -> bf16x8
  float4 f0 = *(const float4*)src;
  float4 f1 = *(const float4*)(src + 4);
  bf16x8 r;
  r[0] = f2bf(f0.x); r[1] = f2bf(f0.y); r[2] = f2bf(f0.z); r[3] = f2bf(f0.w);
  r[4] = f2bf(f1.x); r[5] = f2bf(f1.y); r[6] = f2bf(f1.z); r[7] = f2bf(f1.w);
  return r;
}

// ---------------- Pre-pass 1: K (f32) -> fragment-linear bf16 ----------------
__global__ __launch_bounds__(256) void convert_k_kernel(
    const float* __restrict__ Kg, short* __restrict__ Kp) {
  const int tid = threadIdx.x;
  const int lane = tid & 63, half = (tid >> 6) & 1, sub = tid >> 7;
  const int blk = blockIdx.x;                   // 2048 blocks
  const int bh = blk >> 6;                      // 32
  const int ktile = (((blk & 63) << 1) | sub);  // 0..127
  const int g = lane >> 4, ln = lane & 15;
  const float* src = Kg + ((size_t)bh * L_ + ktile * 16 + ln) * D_ + half * 32 + g * 8;
  bf16x8 f = frag_from(src);
  *(bf16x8*)(Kp + ((size_t)bh * 16384 + ktile * 128 + half * 64 + lane) * 8) = f;
}

// ---------------- Pre-pass 2: V (f32) -> fragment-linear bf16 Vp ----------------
// Vp unit (16B): idx = (bh*8 + c)*2048 + (n*8 + w)*64 + lane, lane=(g,ln):
// {V[k0+e][d] e=0..3, V[k0+16+e][d] e=0..3} bf16, k0 = c*256 + w*32 + g*4,
// d = n*16+ln.  (Exactly one PV B-fragment for the paired-tile mapping.)
__global__ __launch_bounds__(256) void convert_vp_kernel(
    const float* __restrict__ Vg, short* __restrict__ Vp) {
  __shared__ short vt[64 * 256];  // [d][k 0..255] bf16, XOR-swizzled rows of 512B
  const int tid = threadIdx.x;
  const int bh = blockIdx.x >> 3, c = blockIdx.x & 7;
  const float* vb = Vg + (size_t)bh * L_ * D_ + (size_t)c * 256 * D_;
  const int ka = (tid & 127) * 2, dh = (tid >> 7) * 32;
  const float* r0 = vb + (size_t)ka * D_ + dh;
  const float* r1 = r0 + D_;
#pragma unroll
  for (int i = 0; i < 8; ++i) {
    float4 a = *(const float4*)(r0 + i * 4);
    float4 b = *(const float4*)(r1 + i * 4);
    unsigned p0 = pk2(a.x, b.x), p1 = pk2(a.y, b.y), p2 = pk2(a.z, b.z), p3 = pk2(a.w, b.w);
    const int dd = dh + i * 4;
    *(unsigned*)((char*)vt + (dd + 0) * 512 + ((ka * 2) ^ (((dd + 0) & 7) << 4))) = p0;
    *(unsigned*)((char*)vt + (dd + 1) * 512 + ((ka * 2) ^ (((dd + 1) & 7) << 4))) = p1;
    *(unsigned*)((char*)vt + (dd + 2) * 512 + ((ka * 2) ^ (((dd + 2) & 7) << 4))) = p2;
    *(unsigned*)((char*)vt + (dd + 3) * 512 + ((ka * 2) ^ (((dd + 3) & 7) << 4))) = p3;
  }
  __syncthreads();
  u32x4* out = (u32x4*)Vp + (size_t)(bh * 8 + c) * 2048;
#pragma unroll
  for (int i = 0; i < 8; ++i) {
    const int u = tid + 256 * i;
    const int lane = u & 63, w = (u >> 6) & 7, n = u >> 9;
    const int g = lane >> 4, ln = lane & 15;
    const int d = n * 16 + ln;
    const int kb = (w * 32 + g * 4) * 2;  // byte offset of k0 within row
    const char* rowp = (const char*)vt + d * 512;
    const int swz = (d & 7) << 4;
    uint2 lo = *(const uint2*)(rowp + (kb ^ swz));
    uint2 hi = *(const uint2*)(rowp + ((kb + 32) ^ swz));
    out[u] = u32x4{lo.x, lo.y, hi.x, hi.y};
  }
}

// ---------------- Pre-pass 3: mask (f32) -> fragment-linear Mp ----------------
// Mp unit (float4): idx = ((b*128 + qt)*128 + tile)*64 + lane, lane=(g,ln):
// mask[b][qt*16+ln][tile*16+g*4 .. +4].  QK mask loads become coalesced.
__global__ __launch_bounds__(256) void convert_m_kernel(
    const float* __restrict__ Mg, float* __restrict__ Mp) {
  const int tid = threadIdx.x;
  const int b = blockIdx.x >> 7, qt = blockIdx.x & 127;  // 256 blocks
  const float* src = Mg + (size_t)b * L_ * L_ + (size_t)qt * 16 * L_;
  f32x4* out = (f32x4*)Mp + ((size_t)(b * 128 + qt) * 128) * 64;
#pragma unroll
  for (int i = 0; i < 32; ++i) {
    const int u = tid + 256 * i;  // tile*64 + lane
    const int tile = u >> 6, lane = u & 63;
    const int g = (lane >> 4) & 3, ln = lane & 15;
    out[u] = *(const f32x4*)(src + (size_t)ln * L_ + tile * 16 + g * 4);
  }
}

// ---------------- Fused kernel ----------------
// 512 threads (8 waves), q-tile 16 rows. Swapped QK^T: mfma(K,Q); wave w owns
// paired tiles 2w+16i+{0,1} -> full-line P stores. PV: chunk c staged into a
// single 32KB LDS buffer (write-after-read barrier) via T14 async-split.
// 4-head-group decode (r18): FETCH at compulsory minimum. USEMP: mask reads
// from fragment-linear Mp (fully coalesced) instead of 8KB-stride gather.
template <bool USEPRE, bool USEMP>
__global__ __launch_bounds__(512, 4) void attn_fused(
    const float* __restrict__ Qg, const float* __restrict__ Kg,
    const short* __restrict__ Kp, const float* __restrict__ Vg,
    const short* __restrict__ Vpg, const float* __restrict__ Mg,
    const float* __restrict__ Mpg, float* __restrict__ Pg,
    float* __restrict__ Og) {
  const int tid = threadIdx.x;
  const int w = tid >> 6, lane = tid & 63;
  const int g = lane >> 4, ln = lane & 15;

  // 4096 blocks = 8 XCD chunks x 512; chunk = 1 head-group (4 bh) x 128 qt.
  const int bid = blockIdx.x;
  const int wg = (bid & 7) * 512 + (bid >> 3);
  const int grp = wg >> 9;          // 0..7: head group (4 heads)
  const int idx = wg & 511;
  const int qt = idx >> 2;          // 0..127
  const int bh = grp * 4 + (idx & 3);
  const int q0 = qt << 4;
  const int b = bh >> 4;  // H_=16

  __shared__ u32x4 vstage[2048];  // 32 KB single-buffer fragment-linear V chunk
  __shared__ float red[8][16];

  const float* qp = Qg + (size_t)bh * L_ * D_;
  const float* mrow = Mg + (size_t)b * L_ * L_ + (size_t)(q0 + ln) * L_;
  const f32x4* mp4 = (const f32x4*)Mpg + ((size_t)(b * 128 + qt) * 128) * 64 + lane;
  float* prow = Pg + (size_t)bh * L_ * L_ + (size_t)(q0 + ln) * L_;

  bf16x8 qf0 = frag_from(qp + (size_t)(q0 + ln) * D_ + g * 8);
  bf16x8 qf1 = frag_from(qp + (size_t)(q0 + ln) * D_ + 32 + g * 8);

  unsigned pkv[32];
  float mx = -1e30f;
  const bf16x8* kb_ = (const bf16x8*)Kp + (size_t)bh * 16384 + lane;

#define TILE_OF(j) (2 * w + (((j) >> 1) << 4) + ((j) & 1))
#define MK_LOAD(dst, t_)                                                \
  {                                                                     \
    if (USEMP) dst = __builtin_bit_cast(float4, mp4[(t_) * 64]);        \
    else dst = *(const float4*)(mrow + (t_) * 16 + g * 4);              \
  }

  // ---- QK^T with explicit 1-deep prefetch of K-frags and mask ----
  bf16x8 k0c, k1c, k0n, k1n;
  float4 mkc, mkn;
  {
    const int t0 = TILE_OF(0);
    if (USEPRE) {
      k0c = kb_[t0 * 128];
      k1c = kb_[t0 * 128 + 64];
    } else {
      const float* kr = Kg + (size_t)bh * L_ * D_ + (size_t)(t0 * 16 + ln) * D_;
      k0c = frag_from(kr + g * 8);
      k1c = frag_from(kr + 32 + g * 8);
    }
    MK_LOAD(mkc, t0)
  }
#pragma unroll
  for (int j = 0; j < 16; ++j) {
    if (j < 15) {
      const int tn = TILE_OF(j + 1);
      if (USEPRE) {
        k0n = kb_[tn * 128];
        k1n = kb_[tn * 128 + 64];
      } else {
        const float* kr = Kg + (size_t)bh * L_ * D_ + (size_t)(tn * 16 + ln) * D_;
        k0n = frag_from(kr + g * 8);
        k1n = frag_from(kr + 32 + g * 8);
      }
      MK_LOAD(mkn, tn)
    }
    f32x4 acc{0.f, 0.f, 0.f, 0.f};
    acc = __builtin_amdgcn_mfma_f32_16x16x32_bf16(k0c, qf0, acc, 0, 0, 0);
    acc = __builtin_amdgcn_mfma_f32_16x16x32_bf16(k1c, qf1, acc, 0, 0, 0);
    float l0 = acc[0] * SCALE2 * mkc.x;   // log2-domain logits
    float l1 = acc[1] * SCALE2 * mkc.y;
    float l2 = acc[2] * SCALE2 * mkc.z;
    float l3 = acc[3] * SCALE2 * mkc.w;
    mx = fmaxf(mx, fmaxf(fmaxf(l0, l1), fmaxf(l2, l3)));
    pkv[2 * j] = pk2(l0, l1);
    pkv[2 * j + 1] = pk2(l2, l3);
    k0c = k0n; k1c = k1n; mkc = mkn;
  }

  // ---- issue chunk-0 stage loads; land during softmax (T14 split) ----
  const u32x4* vp4 = (const u32x4*)Vpg + (size_t)bh * 8 * 2048;
  u32x4 sv0, sv1, sv2, sv3;
  if (USEPRE) {
    sv0 = vp4[0 * 512 + tid];
    sv1 = vp4[1 * 512 + tid];
    sv2 = vp4[2 * 512 + tid];
    sv3 = vp4[3 * 512 + tid];
  }

  // ---- softmax (q-row ln per lane), exp2 domain ----
  mx = fmaxf(mx, __shfl_xor(mx, 16));
  mx = fmaxf(mx, __shfl_xor(mx, 32));
  if (lane < 16) red[w][ln] = mx;
  __syncthreads();
  {
    float t = red[0][ln];
#pragma unroll
    for (int ww = 1; ww < 8; ++ww) t = fmaxf(t, red[ww][ln]);
    mx = t;
  }
  float sm = 0.f;
#pragma unroll
  for (int j = 0; j < 16; ++j) {
    float e0 = exp2f(bflo(pkv[2 * j]) - mx);
    float e1 = exp2f(bfhi(pkv[2 * j]) - mx);
    float e2 = exp2f(bflo(pkv[2 * j + 1]) - mx);
    float e3 = exp2f(bfhi(pkv[2 * j + 1]) - mx);
    sm += (e0 + e1) + (e2 + e3);
    pkv[2 * j] = pk2(e0, e1);
    pkv[2 * j + 1] = pk2(e2, e3);
  }
  sm += __shfl_xor(sm, 16);
  sm += __shfl_xor(sm, 32);
  __syncthreads();  // max-phase readers done with red
  if (lane < 16) red[w][ln] = sm;
  // write chunk-0 stage to LDS here; ordered before PV reads by the barrier
  if (USEPRE) {
    vstage[0 * 512 + tid] = sv0;
    vstage[1 * 512 + tid] = sv1;
    vstage[2 * 512 + tid] = sv2;
    vstage[3 * 512 + tid] = sv3;
  }
  __syncthreads();
  float inv;
  {
    float t = red[0][ln];
#pragma unroll
    for (int ww = 1; ww < 8; ++ww) t += red[ww][ln];
    inv = 1.0f / t;
  }

  // ---- PV + P-write, chunk c = tile pair (2w+16c, 2w+16c+1) ----
  f32x4 acc_o[4];
#pragma unroll
  for (int n = 0; n < 4; ++n) acc_o[n] = f32x4{0.f, 0.f, 0.f, 0.f};

  const float* vsrc_f32 = Vg + (size_t)bh * L_ * D_;

#pragma unroll
  for (int c = 0; c < 8; ++c) {
    // T14: issue next chunk's global loads FIRST (hide under compute below)
    if (USEPRE && c < 7) {
      sv0 = vp4[(size_t)(c + 1) * 2048 + 0 * 512 + tid];
      sv1 = vp4[(size_t)(c + 1) * 2048 + 1 * 512 + tid];
      sv2 = vp4[(size_t)(c + 1) * 2048 + 2 * 512 + tid];
      sv3 = vp4[(size_t)(c + 1) * 2048 + 3 * 512 + tid];
    }
    // normalize this chunk's 8 P values; store full 128B line per lane-row
    unsigned u0 = pkv[4 * c], u1 = pkv[4 * c + 1], u2 = pkv[4 * c + 2], u3 = pkv[4 * c + 3];
    float n0 = bflo(u0) * inv, n1 = bfhi(u0) * inv;
    float n2 = bflo(u1) * inv, n3 = bfhi(u1) * inv;
    float n4 = bflo(u2) * inv, n5 = bfhi(u2) * inv;
    float n6 = bflo(u3) * inv, n7 = bfhi(u3) * inv;
    const int te = 2 * w + 16 * c;
    f32x4 s0{n0, n1, n2, n3};
    f32x4 s1{n4, n5, n6, n7};
    __builtin_nontemporal_store(s0, (f32x4*)(prow + te * 16 + g * 4));
    __builtin_nontemporal_store(s1, (f32x4*)(prow + (te + 1) * 16 + g * 4));
    u32x4 au{pk2(n0, n1), pk2(n2, n3), pk2(n4, n5), pk2(n6, n7)};
    bf16x8 pa = __builtin_bit_cast(bf16x8, au);
    // MFMA from LDS (fragment-linear: fully conflict-free b128 reads)
#pragma unroll
    for (int n = 0; n < 4; ++n) {
      bf16x8 bf;
      if (USEPRE) {
        bf = __builtin_bit_cast(bf16x8, vstage[(n * 8 + w) * 64 + lane]);
      } else {
        const int k0i = c * 256 + w * 32 + g * 4;
        const int d = n * 16 + ln;
        const float* vbp = vsrc_f32 + d;
#pragma unroll
        for (int e = 0; e < 4; ++e) bf[e] = f2bf(vbp[(size_t)(k0i + e) * D_]);
#pragma unroll
        for (int e = 0; e < 4; ++e) bf[4 + e] = f2bf(vbp[(size_t)(k0i + 16 + e) * D_]);
      }
      acc_o[n] = __builtin_amdgcn_mfma_f32_16x16x32_bf16(pa, bf, acc_o[n], 0, 0, 0);
    }
    __syncthreads();  // all reads of chunk c done
    if (USEPRE && c < 7) {
      vstage[0 * 512 + tid] = sv0;
      vstage[1 * 512 + tid] = sv1;
      vstage[2 * 512 + tid] = sv2;
      vstage[3 * 512 + tid] = sv3;
      __syncthreads();  // chunk c+1 visible
    }
  }

  // ---- 8-way O-partial reduce (alias vstage) + write O ----
  float* red_o = (float*)&vstage[0];  // 32 KB
#pragma unroll
  for (int n = 0; n < 4; ++n)
#pragma unroll
    for (int r = 0; r < 4; ++r)
      red_o[(w * 16 + g * 4 + r) * 64 + n * 16 + ln] = acc_o[n][r];
  __syncthreads();
  {
    float* ob = Og + (size_t)bh * L_ * D_ + (size_t)q0 * D_;
    const int row = tid >> 5, dp = (tid & 31) * 2;
    float s0 = 0.f, s1 = 0.f;
#pragma unroll
    for (int ww = 0; ww < 8; ++ww) {
      s0 += red_o[(ww * 16 + row) * 64 + dp];
      s1 += red_o[(ww * 16 + row) * 64 + dp + 1];
    }
    __builtin_nontemporal_store(s0, ob + row * D_ + dp);
    __builtin_nontemporal_store(s1, ob + row * D_ + dp + 1);
  }
}

extern "C" void kernel_launch(void* const* d_in, const int* in_sizes, int n_in,
                              void* d_out, int out_size, void* d_ws, size_t ws_size,
                              hipStream_t stream) {
  const float* q = (const float*)d_in[0];
  const float* k = (const float*)d_in[1];
  const float* v = (const float*)d_in[2];
  const float* mask = (const float*)d_in[3];
  float* out = (float*)d_out;                      // [B,H,L,D]
  float* score = out + (size_t)B_ * H_ * L_ * D_;  // [B,H,L,L]

  const size_t elems = (size_t)B_ * H_ * L_ * D_;   // 4.19M
  const size_t kv_bytes = elems * 2 * sizeof(short);    // Kp + Vp = 16 MB
  const size_t m_bytes = (size_t)B_ * L_ * L_ * 4;      // Mp = 33.5 MB
  const int nblk = B_ * H_ * (L_ / 16);             // 4096

  if (ws_size >= kv_bytes + m_bytes) {
    short* kp = (short*)d_ws;
    short* vp = kp + elems;
    float* mp = (float*)(vp + elems);
    convert_k_kernel<<<2048, 256, 0, stream>>>(k, kp);
    convert_vp_kernel<<<B_ * H_ * 8, 256, 0, stream>>>(v, vp);
    convert_m_kernel<<<B_ * 128, 256, 0, stream>>>(mask, mp);
    attn_fused<true, true><<<nblk, 512, 0, stream>>>(q, k, kp, v, vp, mask, mp, score, out);
  } else if (ws_size >= kv_bytes) {
    short* kp = (short*)d_ws;
    short* vp = kp + elems;
    convert_k_kernel<<<2048, 256, 0, stream>>>(k, kp);
    convert_vp_kernel<<<B_ * H_ * 8, 256, 0, stream>>>(v, vp);
    attn_fused<true, false><<<nblk, 512, 0, stream>>>(q, k, kp, v, vp, mask, nullptr, score, out);
  } else {
    attn_fused<false, false><<<nblk, 512, 0, stream>>>(q, k, nullptr, v, nullptr, mask, nullptr, score, out);
  }
}